// Round 2
// baseline (87.160 us; speedup 1.0000x reference)
//
#include <hip/hip_runtime.h>
#include <math.h>

#define NB 16
#define T_SEQ 1024
#define DIN 128
#define NH 64

// ---------------------------------------------------------------------------
// k1: Bx[b][h][t] = sum_j B[h][j] * x[b][t][j]
// grid 256 blocks (64 bt-rows each), 256 threads (4 waves).
// Wave w handles h in [16w, 16w+16); lane l handles row = blk*64 + l.
// B staged in LDS (broadcast reads, conflict-free). x read once via float4.
// ---------------------------------------------------------------------------
__global__ __launch_bounds__(256) void k_gemm(const float* __restrict__ x,
                                              const float* __restrict__ Bm,
                                              float* __restrict__ bx) {
    __shared__ float sB[NH * DIN]; // 32 KB
    const int tid = threadIdx.x;
    for (int i = tid; i < NH * DIN / 4; i += 256)
        reinterpret_cast<float4*>(sB)[i] = reinterpret_cast<const float4*>(Bm)[i];
    __syncthreads();

    const int wave = tid >> 6, lane = tid & 63;
    const int row = blockIdx.x * 64 + lane;     // flat (b,t) row
    const int b = row >> 10, t = row & 1023;
    const float* xr = x + (size_t)row * DIN;

    float acc[16];
#pragma unroll
    for (int i = 0; i < 16; ++i) acc[i] = 0.f;

    for (int jc = 0; jc < DIN / 4; ++jc) {
        const float4 xv = reinterpret_cast<const float4*>(xr)[jc];
#pragma unroll
        for (int hh = 0; hh < 16; ++hh) {
            const int h = wave * 16 + hh;
            const float4 bv = reinterpret_cast<const float4*>(sB + h * DIN)[jc];
            acc[hh] += xv.x * bv.x + xv.y * bv.y + xv.z * bv.z + xv.w * bv.w;
        }
    }
#pragma unroll
    for (int hh = 0; hh < 16; ++hh) {
        const int h = wave * 16 + hh;
        bx[((size_t)(b * NH + h) << 10) + t] = acc[hh];
    }
}

// ---------------------------------------------------------------------------
// k2: parallel scan. One wave per (b,h). h_t = lam*h_{t-1} + u_t, h_{-1}=1.
// Lane l owns t in [16l, 16l+16). Local serial scan -> wave Hillis-Steele
// scan with factor lam^16 -> per-lane carry + direct lam^(16l) initial state.
// Reads u from R (the Bx buffer), overwrites R with Re(h), writes Im(h) to I.
// ---------------------------------------------------------------------------
__global__ __launch_bounds__(256) void k_scan(const float* __restrict__ nu,
                                              const float* __restrict__ theta,
                                              float* __restrict__ R,
                                              float* __restrict__ I) {
    const int wave = threadIdx.x >> 6, lane = threadIdx.x & 63;
    const int wid = blockIdx.x * 4 + wave;    // (b,h) pair
    const int h = wid & (NH - 1);

    const float env = expf(nu[h]);
    const float th = theta[h];

    // lam = exp(-env) * (cos th, sin th)
    float s1, c1; sincosf(th, &s1, &c1);
    const float mag1 = expf(-env);
    const float lr = mag1 * c1, li = mag1 * s1;

    float* rowR = R + ((size_t)wid << 10);
    float* rowI = I + ((size_t)wid << 10);

    float pr[16], pi[16];
#pragma unroll
    for (int q = 0; q < 4; ++q) {
        const float4 u4 = reinterpret_cast<const float4*>(rowR + lane * 16)[q];
        pr[q * 4 + 0] = u4.x; pr[q * 4 + 1] = u4.y;
        pr[q * 4 + 2] = u4.z; pr[q * 4 + 3] = u4.w;
    }

    // local inclusive scan over 16 steps (in place)
    float sr = 0.f, si = 0.f;
#pragma unroll
    for (int i = 0; i < 16; ++i) {
        const float u = pr[i];
        const float nr = lr * sr - li * si + u;
        const float ni = lr * si + li * sr;
        pr[i] = nr; pi[i] = ni;
        sr = nr; si = ni;
    }

    // wave scan of chunk aggregates with factor f = lam^16 (direct form)
    float fs_, fc_; sincosf(16.f * th, &fs_, &fc_);
    const float fmag = expf(-16.f * env);
    float dr = fmag * fc_, di = fmag * fs_;   // f^d, doubling
    float vr = sr, vi = si;
#pragma unroll
    for (int d = 1; d < 64; d <<= 1) {
        const float orr = __shfl_up(vr, d, 64);
        const float oii = __shfl_up(vi, d, 64);
        if (lane >= d) {
            vr += dr * orr - di * oii;
            vi += dr * oii + di * orr;
        }
        const float t2r = dr * dr - di * di;
        const float t2i = 2.f * dr * di;
        dr = t2r; di = t2i;
    }

    // exclusive carry + initial-state term lam^(16*lane)
    float cr = __shfl_up(vr, 1, 64);
    float ci = __shfl_up(vi, 1, 64);
    if (lane == 0) { cr = 0.f; ci = 0.f; }
    float gs_, gc_; sincosf(16.f * (float)lane * th, &gs_, &gc_);
    const float gmag = expf(-16.f * (float)lane * env);
    const float gr = cr + gmag * gc_;
    const float gi = ci + gmag * gs_;

    // outputs: h_{16l+i} = lam^{i+1} * G + P_i
    float lpr = lr, lpi = li;
#pragma unroll
    for (int i = 0; i < 16; ++i) {
        const float hr = lpr * gr - lpi * gi + pr[i];
        const float hi = lpr * gi + lpi * gr + pi[i];
        pr[i] = hr; pi[i] = hi;
        const float nr = lpr * lr - lpi * li;
        const float ni = lpr * li + lpi * lr;
        lpr = nr; lpi = ni;
    }

#pragma unroll
    for (int q = 0; q < 4; ++q) {
        float4 o;
        o.x = pr[q * 4 + 0]; o.y = pr[q * 4 + 1];
        o.z = pr[q * 4 + 2]; o.w = pr[q * 4 + 3];
        reinterpret_cast<float4*>(rowR + lane * 16)[q] = o;
        float4 oi;
        oi.x = pi[q * 4 + 0]; oi.y = pi[q * 4 + 1];
        oi.z = pi[q * 4 + 2]; oi.w = pi[q * 4 + 3];
        reinterpret_cast<float4*>(rowI + lane * 16)[q] = oi;
    }
}

// ---------------------------------------------------------------------------
// k3: transpose [b][h][t] (R,I planes) -> out[b][t][ h | 64+h ].
// grid 256 blocks = (b, t-tile of 64). LDS tile [64 t][128 c] (+1 pad).
// Coalesced float4 reads; full 512B-row coalesced dword writes.
// ---------------------------------------------------------------------------
__global__ __launch_bounds__(256) void k_tr(const float* __restrict__ R,
                                            const float* __restrict__ I,
                                            float* __restrict__ out) {
    __shared__ float s[64][129];
    const int b = blockIdx.x >> 4;
    const int t0 = (blockIdx.x & 15) * 64;
    const int tid = threadIdx.x;

#pragma unroll
    for (int k = 0; k < 4; ++k) {
        const int q = tid + k * 256;            // 1024 float4 of R tile
        const int hh = q >> 4, t4 = q & 15;
        const float4 v = reinterpret_cast<const float4*>(
            R + (((size_t)(b * NH + hh) << 10) + t0))[t4];
        s[t4 * 4 + 0][hh] = v.x; s[t4 * 4 + 1][hh] = v.y;
        s[t4 * 4 + 2][hh] = v.z; s[t4 * 4 + 3][hh] = v.w;
    }
#pragma unroll
    for (int k = 0; k < 4; ++k) {
        const int q = tid + k * 256;
        const int hh = q >> 4, t4 = q & 15;
        const float4 v = reinterpret_cast<const float4*>(
            I + (((size_t)(b * NH + hh) << 10) + t0))[t4];
        s[t4 * 4 + 0][64 + hh] = v.x; s[t4 * 4 + 1][64 + hh] = v.y;
        s[t4 * 4 + 2][64 + hh] = v.z; s[t4 * 4 + 3][64 + hh] = v.w;
    }
    __syncthreads();

    const size_t obase = ((size_t)b * T_SEQ + t0) * 128;
#pragma unroll
    for (int k = 0; k < 32; ++k) {
        const int q = tid + k * 256;            // 8192 floats
        out[obase + q] = s[q >> 7][q & 127];
    }
}

extern "C" void kernel_launch(void* const* d_in, const int* in_sizes, int n_in,
                              void* d_out, int out_size, void* d_ws, size_t ws_size,
                              hipStream_t stream) {
    const float* x  = (const float*)d_in[0];
    const float* Bm = (const float*)d_in[1];
    const float* nu = (const float*)d_in[2];
    const float* th = (const float*)d_in[3];
    float* out = (float*)d_out;

    float* R = (float*)d_ws;              // 1M floats: Bx, then Re(h)
    float* I = R + (1 << 20);             // 1M floats: Im(h)

    k_gemm<<<256, 256, 0, stream>>>(x, Bm, R);
    k_scan<<<256, 256, 0, stream>>>(nu, th, R, I);
    k_tr  <<<256, 256, 0, stream>>>(R, I, out);
}